// Round 10
// baseline (1213.845 us; speedup 1.0000x reference)
//
#include <hip/hip_runtime.h>
#include <hip/hip_bf16.h>

#define D 128
#define SSTR 136   // LDS row stride (shorts); 272B => 4-bank shift/row => conflict-free
#define CHUNK 12544  // per-XCD node chunk (multiple of 64); 8*12544 >= N

typedef float f32x4  __attribute__((ext_vector_type(4)));
typedef unsigned int u32x4 __attribute__((ext_vector_type(4)));
typedef __attribute__((ext_vector_type(8))) __bf16 bh8;

union UV { uint4 u; bh8 h; };

__device__ inline float bf2f(unsigned short u) {
    union { unsigned int i; float f; } x; x.i = ((unsigned int)u) << 16; return x.f;
}
__device__ inline unsigned short f2bf(float f) {
    union { float f; unsigned int i; } x; x.f = f;
    return (unsigned short)((x.i + 0x7fffu + ((x.i >> 16) & 1u)) >> 16);
}
__device__ inline unsigned int addb2(unsigned int ua, unsigned int ub) {
    union { unsigned int i; float f; } la, ha, lb, hb;
    la.i = ua << 16; ha.i = ua & 0xffff0000u;
    lb.i = ub << 16; hb.i = ub & 0xffff0000u;
    return ((unsigned int)f2bf(ha.f + hb.f) << 16) | f2bf(la.f + lb.f);
}

// ---------------- CSR build ----------------
__global__ void k_hist(const int* __restrict__ edges, int E, int* __restrict__ deg) {
    int e = blockIdx.x * blockDim.x + threadIdx.x;
    if (e < E) {
        atomicAdd(&deg[edges[2 * e]], 1);
        atomicAdd(&deg[edges[2 * e + 1]], 1);
    }
}

__global__ void k_scan1(const int* __restrict__ deg, int n,
                        int* __restrict__ incl, int* __restrict__ bsum) {
    __shared__ int lds[1024];
    int t = threadIdx.x;
    int i = blockIdx.x * 1024 + t;
    int v = (i < n) ? deg[i] : 0;
    int cur = v;
    lds[t] = cur;
    __syncthreads();
    for (int off = 1; off < 1024; off <<= 1) {
        int add = (t >= off) ? lds[t - off] : 0;
        __syncthreads();
        cur += add;
        lds[t] = cur;
        __syncthreads();
    }
    if (i < n) incl[i] = cur;
    if (t == 1023) bsum[blockIdx.x] = cur;
}

__global__ void k_scan2(int* __restrict__ bsum, int nb) {
    __shared__ int lds[128];
    int t = threadIdx.x;
    int v = (t < nb) ? bsum[t] : 0;
    int cur = v;
    lds[t] = cur;
    __syncthreads();
    for (int off = 1; off < 128; off <<= 1) {
        int add = (t >= off) ? lds[t - off] : 0;
        __syncthreads();
        cur += add;
        lds[t] = cur;
        __syncthreads();
    }
    if (t < nb) bsum[t] = cur - v;  // exclusive
}

__global__ void k_scan3(const int* __restrict__ incl, const int* __restrict__ deg,
                        const int* __restrict__ bsum, int n, int twoE,
                        int* __restrict__ rowstart, int* __restrict__ cursor) {
    int i = blockIdx.x * blockDim.x + threadIdx.x;
    if (i < n) {
        int r = incl[i] - deg[i] + bsum[i >> 10];
        rowstart[i] = r;
        cursor[i] = r;
    }
    if (i == 0) rowstart[n] = twoE;
}

__global__ void k_fill(const int* __restrict__ edges, int E,
                       int* __restrict__ cursor, int* __restrict__ adj) {
    int e = blockIdx.x * blockDim.x + threadIdx.x;
    if (e < E) {
        int a = edges[2 * e], b = edges[2 * e + 1];
        adj[atomicAdd(&cursor[a], 1)] = b;
        adj[atomicAdd(&cursor[b], 1)] = a;
    }
}

// ---------------- weight prep: bf16, K-chunked layout ----------------
// wb[l][chunk=kk>>5][o][kk&31], kk = m*128+k (m=0: W0, m=1: W1)
__global__ void k_wprep(const float* __restrict__ W0_1, const float* __restrict__ W1_1,
                        const float* __restrict__ W0_h, const float* __restrict__ W1_h,
                        unsigned short* __restrict__ wb) {
    int idx = blockIdx.x * 256 + threadIdx.x;
    if (idx >= 13 * 2 * 128 * 128) return;
    int k = idx & 127;
    int o = (idx >> 7) & 127;
    int m = (idx >> 14) & 1;
    int l = idx >> 15;
    const float* src = (l == 0) ? (m ? W1_1 : W0_1)
                                : ((m ? W1_h : W0_h) + (size_t)(l - 1) * 16384);
    float v = src[o * 128 + k];
    int kk = m * 128 + k;
    wb[(size_t)l * 32768 + (kk >> 5) * 4096 + o * 32 + (kk & 31)] = f2bf(v);
}

// ---------------- fp32 -> bf16 convert ----------------
__global__ void k_cvt(const float* __restrict__ in, unsigned short* __restrict__ out, int n4) {
    int i = blockIdx.x * blockDim.x + threadIdx.x;
    if (i >= n4) return;
    f32x4 v = *(const f32x4*)&in[(size_t)i * 4];
    unsigned short u[4];
    #pragma unroll
    for (int j = 0; j < 4; ++j) u[j] = f2bf(v[j]);
    *(uint2*)&out[(size_t)i * 4] = *(uint2*)u;
}

// ---------------- fused layer: gather (-> LDS) + pipelined MFMA GEMM ----------------
// Block = 64 nodes, 4 waves, LDS s-tile [64][SSTR] bf16 (17408 B).
// Phase 1: each wave aggregates 16 nodes (round-9 uint2 two-rows-per-load scheme,
// rowstart boundaries preloaded once per wave), result written straight to LDS —
// the sb buffer and its 51.2MB/layer L2<->L3 round trip are deleted.
// Phase 2: round-9 2-stage register-pipelined GEMM; A kc<4 from global x rows
// (row-major == fragment layout), kc>=4 from the LDS s-tile, B from the 64KB
// L2-broadcast weight array. NO min-waves launch bound (round 1's spill killer).
// Epilogue: bias + deg*b1 + relu -> LDS transpose (reuse tile) -> coalesced
// stores; optional fp32 aux copy and fused residual add.
__global__ __launch_bounds__(256) void k_fused(
    const unsigned short* __restrict__ x,    // [n][128] bf16
    const unsigned short* __restrict__ wb,   // layer weights, chunked [8][128][32] bf16
    const float* __restrict__ b0, const float* __restrict__ b1,
    const int* __restrict__ rowstart, const int* __restrict__ adj,
    const int* __restrict__ deg,
    unsigned short* __restrict__ out,        // [n][128] bf16
    float* __restrict__ out32,               // optional fp32 copy (aux), may be null
    const unsigned short* __restrict__ resid,// optional residual input (bf16)
    unsigned short* __restrict__ zout,       // optional: zout = out + resid
    int n, int do_relu) {
    __shared__ __align__(16) unsigned short LDS[64 * SSTR];  // 17408 B
    int node0 = (blockIdx.x & 7) * CHUNK + (blockIdx.x >> 3) * 64;
    if (node0 >= n) return;
    int t = threadIdx.x;
    int lane = t & 63;
    int wave = t >> 6;

    // ---- phase 1: gather 16 nodes per wave into LDS s-tile ----
    {
        int first = node0 + wave * 16;
        int cnt = n - first; if (cnt > 16) cnt = 16;
        if (cnt > 0) {
            int rl = lane; if (rl > cnt) rl = cnt;
            int rsv = rowstart[first + rl];   // lanes 0..cnt hold boundaries
            int c  = lane & 31;               // bf16 cols 4c..4c+3
            int hi = lane >> 5;               // even/odd edge of batch
            for (int i = 0; i < cnt; ++i) {
                int r0 = __shfl(rsv, i);
                int r1 = __shfl(rsv, i + 1);
                float aa0 = 0.f, aa1 = 0.f, aa2 = 0.f, aa3 = 0.f;
                for (int p = r0; p < r1; p += 8) {
                    int q = p + (lane & 7);
                    int idx = (q < r1) ? adj[q] : adj[r0];
                    uint2 u[4];
                    #pragma unroll
                    for (int k = 0; k < 4; ++k) {
                        int j = __shfl(idx, 2 * k + hi);
                        u[k] = *(const uint2*)&x[(size_t)j * D + c * 4];
                    }
                    #pragma unroll
                    for (int k = 0; k < 4; ++k) {
                        if (p + 2 * k + hi < r1) {
                            union { unsigned int i; float f; } tt;
                            tt.i = u[k].x << 16;          aa0 += tt.f;
                            tt.i = u[k].x & 0xffff0000u;  aa1 += tt.f;
                            tt.i = u[k].y << 16;          aa2 += tt.f;
                            tt.i = u[k].y & 0xffff0000u;  aa3 += tt.f;
                        }
                    }
                }
                aa0 += __shfl_xor(aa0, 32);
                aa1 += __shfl_xor(aa1, 32);
                aa2 += __shfl_xor(aa2, 32);
                aa3 += __shfl_xor(aa3, 32);
                if (hi == 0) {
                    uint2 o;
                    o.x = ((unsigned int)f2bf(aa1) << 16) | f2bf(aa0);
                    o.y = ((unsigned int)f2bf(aa3) << 16) | f2bf(aa2);
                    *(uint2*)&LDS[(wave * 16 + i) * SSTR + c * 4] = o;
                }
            }
        }
    }
    __syncthreads();

    // ---- phase 2: GEMM, 2-stage register pipeline, no barriers in loop ----
    int wm = (wave >> 1) * 32;
    int wn = (wave & 1) * 64;
    int mlane = lane & 15;
    int quad = lane >> 4;

    f32x4 acc[2][4];
    #pragma unroll
    for (int i = 0; i < 2; ++i)
        #pragma unroll
        for (int j = 0; j < 4; ++j) acc[i][j] = (f32x4){0.f, 0.f, 0.f, 0.f};

    uint4 ra[2][2];
    bh8 rb[2][4];
    auto LDK = [&](int kc, int st) {
        #pragma unroll
        for (int i = 0; i < 2; ++i) {
            int r = wm + i * 16 + mlane;
            if (kc < 4) {
                int g = node0 + r;
                uint4 v = {0u, 0u, 0u, 0u};
                if (g < n) v = *(const uint4*)&x[(size_t)g * D + (kc & 3) * 32 + quad * 8];
                ra[st][i] = v;
            } else {
                ra[st][i] = *(const uint4*)&LDS[r * SSTR + (kc - 4) * 32 + quad * 8];
            }
        }
        #pragma unroll
        for (int j = 0; j < 4; ++j)
            rb[st][j] = *(const bh8*)&wb[(size_t)kc * 4096 + (wn + j * 16 + mlane) * 32 + quad * 8];
    };

    LDK(0, 0);
    #pragma unroll
    for (int kc = 0; kc < 8; ++kc) {
        int cs = kc & 1;
        if (kc < 7) LDK(kc + 1, cs ^ 1);   // issue next-chunk loads before MFMAs
        bh8 a0, a1;
        { UV v; v.u = ra[cs][0]; a0 = v.h; }
        { UV v; v.u = ra[cs][1]; a1 = v.h; }
        #pragma unroll
        for (int j = 0; j < 4; ++j) {
            acc[0][j] = __builtin_amdgcn_mfma_f32_16x16x32_bf16(a0, rb[cs][j], acc[0][j], 0, 0, 0);
            acc[1][j] = __builtin_amdgcn_mfma_f32_16x16x32_bf16(a1, rb[cs][j], acc[1][j], 0, 0, 0);
        }
    }

    // ---- epilogue: bias + deg*b1 + relu -> LDS transpose -> coalesced stores ----
    __syncthreads();   // all s-tile reads done; reuse LDS as O-tile
    #pragma unroll
    for (int i = 0; i < 2; ++i) {
        int mrow = wm + i * 16 + quad * 4;
        #pragma unroll
        for (int j = 0; j < 4; ++j) {
            int nn = wn + j * 16 + mlane;
            float b0v = b0[nn], b1v = b1[nn];
            #pragma unroll
            for (int r = 0; r < 4; ++r) {
                int g = node0 + mrow + r;
                float dg = (g < n) ? (float)deg[g] : 0.f;
                float val = acc[i][j][r] + b0v + dg * b1v;
                if (do_relu) val = fmaxf(val, 0.f);
                LDS[(mrow + r) * SSTR + nn] = f2bf(val);
            }
        }
    }
    __syncthreads();
    // bf16 store: 4 passes, 16 lanes x 16B = one full 256B node row per 16 threads
    #pragma unroll
    for (int pass = 0; pass < 4; ++pass) {
        int row = pass * 16 + (t >> 4);
        int seg = (t & 15) * 8;
        int g = node0 + row;
        if (g < n) {
            u32x4 v = *(const u32x4*)&LDS[row * SSTR + seg];
            *(u32x4*)&out[(size_t)g * D + seg] = v;
            if (zout) {
                u32x4 rr = *(const u32x4*)&resid[(size_t)g * D + seg];
                u32x4 zz;
                zz.x = addb2(v.x, rr.x);
                zz.y = addb2(v.y, rr.y);
                zz.z = addb2(v.z, rr.z);
                zz.w = addb2(v.w, rr.w);
                *(u32x4*)&zout[(size_t)g * D + seg] = zz;
            }
        }
    }
    if (out32) {
        #pragma unroll
        for (int pass = 0; pass < 8; ++pass) {
            int row = pass * 8 + (t >> 5);
            int seg = (t & 31) * 4;
            int g = node0 + row;
            if (g < n) {
                f32x4 v;
                #pragma unroll
                for (int j = 0; j < 4; ++j) v[j] = bf2f(LDS[row * SSTR + seg + j]);
                *(f32x4*)&out32[(size_t)g * D + seg] = v;
            }
        }
    }
}

// ---------------- fused final layer: aggregate in registers + D_out=3 dot ----------------
// wave per node, two-rows-per-load gather; lane holds 4 cols. 5-step half-wave
// shuffle reduce. Deletes the final sb round-trip and one dispatch.
__global__ __launch_bounds__(256) void k_lastagg(
    const unsigned short* __restrict__ z, const int* __restrict__ rowstart,
    const int* __restrict__ adj,
    const float* __restrict__ W0, const float* __restrict__ b0,
    const float* __restrict__ W1, const float* __restrict__ b1,
    float* __restrict__ vert, int n) {
    int node = blockIdx.x * 4 + (threadIdx.x >> 6);
    int lane = threadIdx.x & 63;
    if (node >= n) return;
    int r0 = rowstart[node], r1 = rowstart[node + 1];
    int c  = lane & 31;
    int hi = lane >> 5;
    float aa0 = 0.f, aa1 = 0.f, aa2 = 0.f, aa3 = 0.f;
    for (int p = r0; p < r1; p += 8) {
        int q = p + (lane & 7);
        int idx = (q < r1) ? adj[q] : adj[r0];
        uint2 u[4];
        #pragma unroll
        for (int k = 0; k < 4; ++k) {
            int j = __shfl(idx, 2 * k + hi);
            u[k] = *(const uint2*)&z[(size_t)j * D + c * 4];
        }
        #pragma unroll
        for (int k = 0; k < 4; ++k) {
            if (p + 2 * k + hi < r1) {
                union { unsigned int i; float f; } t;
                t.i = u[k].x << 16;          aa0 += t.f;
                t.i = u[k].x & 0xffff0000u;  aa1 += t.f;
                t.i = u[k].y << 16;          aa2 += t.f;
                t.i = u[k].y & 0xffff0000u;  aa3 += t.f;
            }
        }
    }
    aa0 += __shfl_xor(aa0, 32);
    aa1 += __shfl_xor(aa1, 32);
    aa2 += __shfl_xor(aa2, 32);
    aa3 += __shfl_xor(aa3, 32);
    // own row z[node], cols 4c..4c+3 (both halves load identical values)
    uint2 zz = *(const uint2*)&z[(size_t)node * D + c * 4];
    float z0, z1, z2, z3;
    { union { unsigned int i; float f; } t;
      t.i = zz.x << 16;         z0 = t.f;
      t.i = zz.x & 0xffff0000u; z1 = t.f;
      t.i = zz.y << 16;         z2 = t.f;
      t.i = zz.y & 0xffff0000u; z3 = t.f; }
    float dg = (float)(r1 - r0);
    #pragma unroll
    for (int o = 0; o < 3; ++o) {
        f32x4 w0 = *(const f32x4*)&W0[o * D + 4 * c];
        f32x4 w1 = *(const f32x4*)&W1[o * D + 4 * c];
        float p = z0 * w0[0] + z1 * w0[1] + z2 * w0[2] + z3 * w0[3]
                + aa0 * w1[0] + aa1 * w1[1] + aa2 * w1[2] + aa3 * w1[3];
        p += __shfl_xor(p, 16);
        p += __shfl_xor(p, 8);
        p += __shfl_xor(p, 4);
        p += __shfl_xor(p, 2);
        p += __shfl_xor(p, 1);
        if (lane == 0) vert[(size_t)node * 3 + o] = p + b0[o] + dg * b1[o];
    }
}

extern "C" void kernel_launch(void* const* d_in, const int* in_sizes, int n_in,
                              void* d_out, int out_size, void* d_ws, size_t ws_size,
                              hipStream_t stream) {
    const float* features = (const float*)d_in[0];
    const int*   edges    = (const int*)d_in[1];
    const float* W0_1 = (const float*)d_in[2];
    const float* b0_1 = (const float*)d_in[3];
    const float* W1_1 = (const float*)d_in[4];
    const float* b1_1 = (const float*)d_in[5];
    const float* W0_h = (const float*)d_in[6];
    const float* b0_h = (const float*)d_in[7];
    const float* W1_h = (const float*)d_in[8];
    const float* b1_h = (const float*)d_in[9];
    const float* W0_l = (const float*)d_in[10];
    const float* b0_l = (const float*)d_in[11];
    const float* W1_l = (const float*)d_in[12];
    const float* b1_l = (const float*)d_in[13];

    const int N_ = 100000, E_ = 300000;
    float* vert = (float*)d_out;                    // N*3
    float* aux  = (float*)d_out + (size_t)N_ * 3;   // N*128 fp32

    char* w = (char*)d_ws;
    auto alloc = [&](size_t bytes) {
        char* p = w;
        w += (bytes + 255) & ~(size_t)255;
        return p;
    };
    unsigned short* wb    = (unsigned short*)alloc((size_t)13 * 32768 * 2);
    unsigned short* xf    = (unsigned short*)alloc((size_t)N_ * D * 2);
    unsigned short* resid = (unsigned short*)alloc((size_t)N_ * D * 2);
    unsigned short* xa    = (unsigned short*)alloc((size_t)N_ * D * 2);
    unsigned short* xb    = (unsigned short*)alloc((size_t)N_ * D * 2);
    int* deg    = (int*)alloc((size_t)N_ * 4);
    int* incl   = (int*)alloc((size_t)N_ * 4);
    int* rowst  = (int*)alloc((size_t)(N_ + 1) * 4);
    int* cursor = (int*)alloc((size_t)N_ * 4);
    int* bsum   = (int*)alloc(128 * 4);
    int* adj    = (int*)alloc((size_t)2 * E_ * 4);

    // CSR build
    hipMemsetAsync(deg, 0, (size_t)N_ * 4, stream);
    k_hist<<<(E_ + 255) / 256, 256, 0, stream>>>(edges, E_, deg);
    int nb = (N_ + 1023) / 1024;   // 98
    k_scan1<<<nb, 1024, 0, stream>>>(deg, N_, incl, bsum);
    k_scan2<<<1, 128, 0, stream>>>(bsum, nb);
    k_scan3<<<(N_ + 255) / 256, 256, 0, stream>>>(incl, deg, bsum, N_, 2 * E_, rowst, cursor);
    k_fill<<<(E_ + 255) / 256, 256, 0, stream>>>(edges, E_, cursor, adj);

    // weight + feature conversion
    k_wprep<<<(13 * 2 * 16384 + 255) / 256, 256, 0, stream>>>(W0_1, W1_1, W0_h, W1_h, wb);
    k_cvt<<<(N_ * D / 4 + 255) / 256, 256, 0, stream>>>(features, xf, N_ * D / 4);

    // XCD-chunked fused grid: xcd = blockIdx%8, 64-node blocks
    int gblocks = 8 * ((CHUNK) / 64);    // 8 * 196 = 1568
    int lblocks = (N_ + 3) / 4;          // k_lastagg

    // layer 1: xf -> resid
    k_fused<<<gblocks, 256, 0, stream>>>(xf, wb, b0_1, b1_1, rowst, adj, deg,
                                         resid, nullptr, nullptr, nullptr, N_, 1);

    // 12 hidden layers; layer 12 also writes aux (fp32) and z = resid + x12 -> xf
    for (int h = 0; h < 12; ++h) {
        const unsigned short* in = (h == 0) ? resid : ((h & 1) ? xa : xb);
        unsigned short* outp = (h & 1) ? xb : xa;
        float* o32 = (h == 11) ? aux : nullptr;
        const unsigned short* radd = (h == 11) ? resid : nullptr;
        unsigned short* zo = (h == 11) ? xf : nullptr;
        k_fused<<<gblocks, 256, 0, stream>>>(in, wb + (size_t)(1 + h) * 32768,
                                             b0_h + h * 128, b1_h + h * 128,
                                             rowst, adj, deg, outp, o32, radd, zo, N_, 1);
    }

    // last layer fused: z (in xf) -> vertices, aggregation kept in registers
    k_lastagg<<<lblocks, 256, 0, stream>>>(xf, rowst, adj, W0_l, b0_l, W1_l, b1_l,
                                           vert, N_);
}

// Round 11
// 1143.491 us; speedup vs baseline: 1.0615x; 1.0615x over previous
//
#include <hip/hip_runtime.h>
#include <hip/hip_bf16.h>

#define D 128
#define OSTR 136   // LDS row stride (shorts) for epilogue transpose
#define CHUNK 12544  // per-XCD node chunk (multiple of 64); 8*12544 >= N

typedef float f32x4  __attribute__((ext_vector_type(4)));
typedef unsigned int u32x4 __attribute__((ext_vector_type(4)));
typedef __attribute__((ext_vector_type(8))) __bf16 bh8;

union UV { uint4 u; bh8 h; };

__device__ inline float bf2f(unsigned short u) {
    union { unsigned int i; float f; } x; x.i = ((unsigned int)u) << 16; return x.f;
}
__device__ inline unsigned short f2bf(float f) {
    union { float f; unsigned int i; } x; x.f = f;
    return (unsigned short)((x.i + 0x7fffu + ((x.i >> 16) & 1u)) >> 16);
}
__device__ inline unsigned int addb2(unsigned int ua, unsigned int ub) {
    union { unsigned int i; float f; } la, ha, lb, hb;
    la.i = ua << 16; ha.i = ua & 0xffff0000u;
    lb.i = ub << 16; hb.i = ub & 0xffff0000u;
    return ((unsigned int)f2bf(ha.f + hb.f) << 16) | f2bf(la.f + lb.f);
}
__device__ inline void acc8(const uint4& u, float* aa) {
    union { unsigned int i; float f; } t;
    t.i = u.x << 16;          aa[0] += t.f;
    t.i = u.x & 0xffff0000u;  aa[1] += t.f;
    t.i = u.y << 16;          aa[2] += t.f;
    t.i = u.y & 0xffff0000u;  aa[3] += t.f;
    t.i = u.z << 16;          aa[4] += t.f;
    t.i = u.z & 0xffff0000u;  aa[5] += t.f;
    t.i = u.w << 16;          aa[6] += t.f;
    t.i = u.w & 0xffff0000u;  aa[7] += t.f;
}

// ---------------- CSR build ----------------
__global__ void k_hist(const int* __restrict__ edges, int E, int* __restrict__ deg) {
    int e = blockIdx.x * blockDim.x + threadIdx.x;
    if (e < E) {
        atomicAdd(&deg[edges[2 * e]], 1);
        atomicAdd(&deg[edges[2 * e + 1]], 1);
    }
}

__global__ void k_scan1(const int* __restrict__ deg, int n,
                        int* __restrict__ incl, int* __restrict__ bsum) {
    __shared__ int lds[1024];
    int t = threadIdx.x;
    int i = blockIdx.x * 1024 + t;
    int v = (i < n) ? deg[i] : 0;
    int cur = v;
    lds[t] = cur;
    __syncthreads();
    for (int off = 1; off < 1024; off <<= 1) {
        int add = (t >= off) ? lds[t - off] : 0;
        __syncthreads();
        cur += add;
        lds[t] = cur;
        __syncthreads();
    }
    if (i < n) incl[i] = cur;
    if (t == 1023) bsum[blockIdx.x] = cur;
}

__global__ void k_scan2(int* __restrict__ bsum, int nb) {
    __shared__ int lds[128];
    int t = threadIdx.x;
    int v = (t < nb) ? bsum[t] : 0;
    int cur = v;
    lds[t] = cur;
    __syncthreads();
    for (int off = 1; off < 128; off <<= 1) {
        int add = (t >= off) ? lds[t - off] : 0;
        __syncthreads();
        cur += add;
        lds[t] = cur;
        __syncthreads();
    }
    if (t < nb) bsum[t] = cur - v;  // exclusive
}

__global__ void k_scan3(const int* __restrict__ incl, const int* __restrict__ deg,
                        const int* __restrict__ bsum, int n, int twoE,
                        int* __restrict__ rowstart, int* __restrict__ cursor) {
    int i = blockIdx.x * blockDim.x + threadIdx.x;
    if (i < n) {
        int r = incl[i] - deg[i] + bsum[i >> 10];
        rowstart[i] = r;
        cursor[i] = r;
    }
    if (i == 0) rowstart[n] = twoE;
}

__global__ void k_fill(const int* __restrict__ edges, int E,
                       int* __restrict__ cursor, int* __restrict__ adj) {
    int e = blockIdx.x * blockDim.x + threadIdx.x;
    if (e < E) {
        int a = edges[2 * e], b = edges[2 * e + 1];
        adj[atomicAdd(&cursor[a], 1)] = b;
        adj[atomicAdd(&cursor[b], 1)] = a;
    }
}

// ---------------- weight prep: bf16, K-chunked layout ----------------
// wb[l][chunk=kk>>5][o][kk&31], kk = m*128+k (m=0: W0, m=1: W1)
__global__ void k_wprep(const float* __restrict__ W0_1, const float* __restrict__ W1_1,
                        const float* __restrict__ W0_h, const float* __restrict__ W1_h,
                        unsigned short* __restrict__ wb) {
    int idx = blockIdx.x * 256 + threadIdx.x;
    if (idx >= 13 * 2 * 128 * 128) return;
    int k = idx & 127;
    int o = (idx >> 7) & 127;
    int m = (idx >> 14) & 1;
    int l = idx >> 15;
    const float* src = (l == 0) ? (m ? W1_1 : W0_1)
                                : ((m ? W1_h : W0_h) + (size_t)(l - 1) * 16384);
    float v = src[o * 128 + k];
    int kk = m * 128 + k;
    wb[(size_t)l * 32768 + (kk >> 5) * 4096 + o * 32 + (kk & 31)] = f2bf(v);
}

// ---------------- fp32 -> bf16 convert ----------------
__global__ void k_cvt(const float* __restrict__ in, unsigned short* __restrict__ out, int n4) {
    int i = blockIdx.x * blockDim.x + threadIdx.x;
    if (i >= n4) return;
    f32x4 v = *(const f32x4*)&in[(size_t)i * 4];
    unsigned short u[4];
    #pragma unroll
    for (int j = 0; j < 4; ++j) u[j] = f2bf(v[j]);
    *(uint2*)&out[(size_t)i * 4] = *(uint2*)u;
}

// ---------------- neighbor aggregation (bf16 in/out, fp32 accum) ----------------
// wave per node, FOUR neighbor rows in flight per load round: 16 lanes x uint4
// (16B = 8 bf16 cols) = one full 256B row per load instruction; lane group
// g = lane>>4 serves edge 4k+g of the 8-edge batch. Per batch: 2 shfl + 2 loads
// (vs 4+4 in the uint2 scheme). Combine via shfl_xor(16)+shfl_xor(32); lanes
// 0-15 store the full row as one uint4.
__global__ __launch_bounds__(256) void k_agg(
    const unsigned short* __restrict__ x, const int* __restrict__ rowstart,
    const int* __restrict__ adj, unsigned short* __restrict__ s, int n) {
    int node = (blockIdx.x & 7) * CHUNK + (blockIdx.x >> 3) * 4 + (threadIdx.x >> 6);
    int lane = threadIdx.x & 63;
    if (node >= n) return;
    int r0 = rowstart[node], r1 = rowstart[node + 1];
    int c = lane & 15;      // col group: bf16 cols 8c..8c+7
    int g = lane >> 4;      // edge subgroup 0..3
    float aa[8];
    #pragma unroll
    for (int k = 0; k < 8; ++k) aa[k] = 0.f;
    for (int p = r0; p < r1; p += 8) {
        int q = p + (lane & 7);
        int idx = (q < r1) ? adj[q] : adj[r0];
        int j0 = __shfl(idx, g);
        int j1 = __shfl(idx, 4 + g);
        uint4 u0 = *(const uint4*)&x[(size_t)j0 * D + c * 8];
        uint4 u1 = *(const uint4*)&x[(size_t)j1 * D + c * 8];
        if (p + g < r1) acc8(u0, aa);
        if (p + 4 + g < r1) acc8(u1, aa);
    }
    #pragma unroll
    for (int k = 0; k < 8; ++k) {
        aa[k] += __shfl_xor(aa[k], 16);
        aa[k] += __shfl_xor(aa[k], 32);
    }
    if (g == 0) {
        unsigned short o[8];
        #pragma unroll
        for (int k = 0; k < 8; ++k) o[k] = f2bf(aa[k]);
        *(uint4*)&s[(size_t)node * D + c * 8] = *(const uint4*)o;
    }
}

// ---------------- MFMA GEMM: 64x128 tile, 2-stage register pipeline ----------------
// out[i][o] = act([x_i, s_i] @ [W0T;W1T] + b0 + deg*b1)
// 256 threads = 4 waves; block tile 64 nodes x 128 outs; K=256 in 8 chunks of 32.
// kc loop software-pipelined in REGISTERS: while MFMAs consume stage cs, the 6
// fragment loads of kc+1 are already in flight into stage cs^1. No LDS/barriers
// in the main loop. All stores CACHED (out is 6x-reused by next layer's gather).
__global__ __launch_bounds__(256) void k_gemm(
    const unsigned short* __restrict__ x,   // [n][128] bf16
    const unsigned short* __restrict__ s,   // [n][128] bf16
    const unsigned short* __restrict__ wb,  // layer weights, chunked [8][128][32] bf16
    const float* __restrict__ b0, const float* __restrict__ b1,
    const int* __restrict__ deg,
    unsigned short* __restrict__ out,       // [n][128] bf16
    float* __restrict__ out32,              // optional fp32 copy (aux), may be null
    const unsigned short* __restrict__ resid, // optional residual input (bf16)
    unsigned short* __restrict__ zout,      // optional: zout = out + resid
    int n, int do_relu) {
    __shared__ __align__(16) unsigned short LDS[64 * OSTR];  // 17408 B (epilogue only)
    int node0 = (blockIdx.x & 7) * CHUNK + (blockIdx.x >> 3) * 64;
    if (node0 >= n) return;
    int t = threadIdx.x;
    int lane = t & 63;
    int wave = t >> 6;
    int wm = (wave >> 1) * 32;
    int wn = (wave & 1) * 64;
    int mlane = lane & 15;
    int quad = lane >> 4;

    f32x4 acc[2][4];
    #pragma unroll
    for (int i = 0; i < 2; ++i)
        #pragma unroll
        for (int j = 0; j < 4; ++j) acc[i][j] = (f32x4){0.f, 0.f, 0.f, 0.f};

    uint4 ra[2][2];
    bh8 rb[2][4];
    auto LDK = [&](int kc, int st) {
        const unsigned short* srcA = (kc < 4) ? x : s;
        int kbase = (kc & 3) * 32;
        #pragma unroll
        for (int i = 0; i < 2; ++i) {
            int g = node0 + wm + i * 16 + mlane;
            uint4 v = {0u, 0u, 0u, 0u};
            if (g < n) v = *(const uint4*)&srcA[(size_t)g * D + kbase + quad * 8];
            ra[st][i] = v;
        }
        #pragma unroll
        for (int j = 0; j < 4; ++j)
            rb[st][j] = *(const bh8*)&wb[(size_t)kc * 4096 + (wn + j * 16 + mlane) * 32 + quad * 8];
    };

    LDK(0, 0);
    #pragma unroll
    for (int kc = 0; kc < 8; ++kc) {
        int cs = kc & 1;
        if (kc < 7) LDK(kc + 1, cs ^ 1);   // issue next-chunk loads before MFMAs
        bh8 a0, a1;
        { UV v; v.u = ra[cs][0]; a0 = v.h; }
        { UV v; v.u = ra[cs][1]; a1 = v.h; }
        #pragma unroll
        for (int j = 0; j < 4; ++j) {
            acc[0][j] = __builtin_amdgcn_mfma_f32_16x16x32_bf16(a0, rb[cs][j], acc[0][j], 0, 0, 0);
            acc[1][j] = __builtin_amdgcn_mfma_f32_16x16x32_bf16(a1, rb[cs][j], acc[1][j], 0, 0, 0);
        }
    }

    // ---- epilogue: bias + deg*b1 + relu -> LDS transpose -> coalesced stores ----
    #pragma unroll
    for (int i = 0; i < 2; ++i) {
        int mrow = wm + i * 16 + quad * 4;
        #pragma unroll
        for (int j = 0; j < 4; ++j) {
            int nn = wn + j * 16 + mlane;
            float b0v = b0[nn], b1v = b1[nn];
            #pragma unroll
            for (int r = 0; r < 4; ++r) {
                int g = node0 + mrow + r;
                float dg = (g < n) ? (float)deg[g] : 0.f;
                float val = acc[i][j][r] + b0v + dg * b1v;
                if (do_relu) val = fmaxf(val, 0.f);
                LDS[(mrow + r) * OSTR + nn] = f2bf(val);
            }
        }
    }
    __syncthreads();
    // bf16 store: 4 passes, 16 lanes x 16B = one full 256B node row per 16 threads
    #pragma unroll
    for (int pass = 0; pass < 4; ++pass) {
        int row = pass * 16 + (t >> 4);
        int seg = (t & 15) * 8;
        int g = node0 + row;
        if (g < n) {
            u32x4 v = *(const u32x4*)&LDS[row * OSTR + seg];
            *(u32x4*)&out[(size_t)g * D + seg] = v;
            if (zout) {
                u32x4 rr = *(const u32x4*)&resid[(size_t)g * D + seg];
                u32x4 zz;
                zz.x = addb2(v.x, rr.x);
                zz.y = addb2(v.y, rr.y);
                zz.z = addb2(v.z, rr.z);
                zz.w = addb2(v.w, rr.w);
                *(u32x4*)&zout[(size_t)g * D + seg] = zz;
            }
        }
    }
    if (out32) {
        #pragma unroll
        for (int pass = 0; pass < 8; ++pass) {
            int row = pass * 8 + (t >> 5);
            int seg = (t & 31) * 4;
            int g = node0 + row;
            if (g < n) {
                f32x4 v;
                #pragma unroll
                for (int j = 0; j < 4; ++j) v[j] = bf2f(LDS[row * OSTR + seg + j]);
                *(f32x4*)&out32[(size_t)g * D + seg] = v;
            }
        }
    }
}

// ---------------- fused final layer: aggregate in registers + D_out=3 dot ----------------
// wave per node, uint4 quarter-wave gather (full 256B row per load, 4 rows in
// flight). After combine all lanes hold the 8-col sums for cols 8c..8c+7; the
// D_out=3 dots use 8 cols/lane and a 4-step 16-lane shfl reduce.
__global__ __launch_bounds__(256) void k_lastagg(
    const unsigned short* __restrict__ z, const int* __restrict__ rowstart,
    const int* __restrict__ adj,
    const float* __restrict__ W0, const float* __restrict__ b0,
    const float* __restrict__ W1, const float* __restrict__ b1,
    float* __restrict__ vert, int n) {
    int node = blockIdx.x * 4 + (threadIdx.x >> 6);
    int lane = threadIdx.x & 63;
    if (node >= n) return;
    int r0 = rowstart[node], r1 = rowstart[node + 1];
    int c = lane & 15;
    int g = lane >> 4;
    float aa[8];
    #pragma unroll
    for (int k = 0; k < 8; ++k) aa[k] = 0.f;
    for (int p = r0; p < r1; p += 8) {
        int q = p + (lane & 7);
        int idx = (q < r1) ? adj[q] : adj[r0];
        int j0 = __shfl(idx, g);
        int j1 = __shfl(idx, 4 + g);
        uint4 u0 = *(const uint4*)&z[(size_t)j0 * D + c * 8];
        uint4 u1 = *(const uint4*)&z[(size_t)j1 * D + c * 8];
        if (p + g < r1) acc8(u0, aa);
        if (p + 4 + g < r1) acc8(u1, aa);
    }
    #pragma unroll
    for (int k = 0; k < 8; ++k) {
        aa[k] += __shfl_xor(aa[k], 16);
        aa[k] += __shfl_xor(aa[k], 32);
    }
    // own row z[node], cols 8c..8c+7 (all four groups load identical values)
    float zf[8];
    {
        uint4 zz = *(const uint4*)&z[(size_t)node * D + c * 8];
        union { unsigned int i; float f; } t;
        t.i = zz.x << 16;          zf[0] = t.f;
        t.i = zz.x & 0xffff0000u;  zf[1] = t.f;
        t.i = zz.y << 16;          zf[2] = t.f;
        t.i = zz.y & 0xffff0000u;  zf[3] = t.f;
        t.i = zz.z << 16;          zf[4] = t.f;
        t.i = zz.z & 0xffff0000u;  zf[5] = t.f;
        t.i = zz.w << 16;          zf[6] = t.f;
        t.i = zz.w & 0xffff0000u;  zf[7] = t.f;
    }
    float dg = (float)(r1 - r0);
    #pragma unroll
    for (int o = 0; o < 3; ++o) {
        f32x4 w0a = *(const f32x4*)&W0[o * D + 8 * c];
        f32x4 w0b = *(const f32x4*)&W0[o * D + 8 * c + 4];
        f32x4 w1a = *(const f32x4*)&W1[o * D + 8 * c];
        f32x4 w1b = *(const f32x4*)&W1[o * D + 8 * c + 4];
        float p = zf[0] * w0a[0] + zf[1] * w0a[1] + zf[2] * w0a[2] + zf[3] * w0a[3]
                + zf[4] * w0b[0] + zf[5] * w0b[1] + zf[6] * w0b[2] + zf[7] * w0b[3]
                + aa[0] * w1a[0] + aa[1] * w1a[1] + aa[2] * w1a[2] + aa[3] * w1a[3]
                + aa[4] * w1b[0] + aa[5] * w1b[1] + aa[6] * w1b[2] + aa[7] * w1b[3];
        p += __shfl_xor(p, 8);
        p += __shfl_xor(p, 4);
        p += __shfl_xor(p, 2);
        p += __shfl_xor(p, 1);
        if (lane == 0) vert[(size_t)node * 3 + o] = p + b0[o] + dg * b1[o];
    }
}

extern "C" void kernel_launch(void* const* d_in, const int* in_sizes, int n_in,
                              void* d_out, int out_size, void* d_ws, size_t ws_size,
                              hipStream_t stream) {
    const float* features = (const float*)d_in[0];
    const int*   edges    = (const int*)d_in[1];
    const float* W0_1 = (const float*)d_in[2];
    const float* b0_1 = (const float*)d_in[3];
    const float* W1_1 = (const float*)d_in[4];
    const float* b1_1 = (const float*)d_in[5];
    const float* W0_h = (const float*)d_in[6];
    const float* b0_h = (const float*)d_in[7];
    const float* W1_h = (const float*)d_in[8];
    const float* b1_h = (const float*)d_in[9];
    const float* W0_l = (const float*)d_in[10];
    const float* b0_l = (const float*)d_in[11];
    const float* W1_l = (const float*)d_in[12];
    const float* b1_l = (const float*)d_in[13];

    const int N_ = 100000, E_ = 300000;
    float* vert = (float*)d_out;                    // N*3
    float* aux  = (float*)d_out + (size_t)N_ * 3;   // N*128 fp32

    char* w = (char*)d_ws;
    auto alloc = [&](size_t bytes) {
        char* p = w;
        w += (bytes + 255) & ~(size_t)255;
        return p;
    };
    unsigned short* wb    = (unsigned short*)alloc((size_t)13 * 32768 * 2);
    unsigned short* xf    = (unsigned short*)alloc((size_t)N_ * D * 2);
    unsigned short* resid = (unsigned short*)alloc((size_t)N_ * D * 2);
    unsigned short* xa    = (unsigned short*)alloc((size_t)N_ * D * 2);
    unsigned short* xb    = (unsigned short*)alloc((size_t)N_ * D * 2);
    unsigned short* sb    = (unsigned short*)alloc((size_t)N_ * D * 2);
    int* deg    = (int*)alloc((size_t)N_ * 4);
    int* incl   = (int*)alloc((size_t)N_ * 4);
    int* rowst  = (int*)alloc((size_t)(N_ + 1) * 4);
    int* cursor = (int*)alloc((size_t)N_ * 4);
    int* bsum   = (int*)alloc(128 * 4);
    int* adj    = (int*)alloc((size_t)2 * E_ * 4);

    // CSR build
    hipMemsetAsync(deg, 0, (size_t)N_ * 4, stream);
    k_hist<<<(E_ + 255) / 256, 256, 0, stream>>>(edges, E_, deg);
    int nb = (N_ + 1023) / 1024;   // 98
    k_scan1<<<nb, 1024, 0, stream>>>(deg, N_, incl, bsum);
    k_scan2<<<1, 128, 0, stream>>>(bsum, nb);
    k_scan3<<<(N_ + 255) / 256, 256, 0, stream>>>(incl, deg, bsum, N_, 2 * E_, rowst, cursor);
    k_fill<<<(E_ + 255) / 256, 256, 0, stream>>>(edges, E_, cursor, adj);

    // weight + feature conversion
    k_wprep<<<(13 * 2 * 16384 + 255) / 256, 256, 0, stream>>>(W0_1, W1_1, W0_h, W1_h, wb);
    k_cvt<<<(N_ * D / 4 + 255) / 256, 256, 0, stream>>>(features, xf, N_ * D / 4);

    // XCD-chunked grids: xcd = blockIdx%8, chunk = CHUNK nodes
    int gblocks = 8 * ((CHUNK) / 64);    // 8 * 196 = 1568
    int ablocks = 8 * ((CHUNK) / 4);     // 8 * 3136 = 25088
    int lblocks = (N_ + 3) / 4;          // k_lastagg

    // layer 1: xf -> resid
    k_agg<<<ablocks, 256, 0, stream>>>(xf, rowst, adj, sb, N_);
    k_gemm<<<gblocks, 256, 0, stream>>>(xf, sb, wb, b0_1, b1_1, deg, resid,
                                        nullptr, nullptr, nullptr, N_, 1);

    // 12 hidden layers; layer 12 also writes aux (fp32) and z = resid + x12 -> xf
    for (int h = 0; h < 12; ++h) {
        const unsigned short* in = (h == 0) ? resid : ((h & 1) ? xa : xb);
        unsigned short* outp = (h & 1) ? xb : xa;
        float* o32 = (h == 11) ? aux : nullptr;
        const unsigned short* radd = (h == 11) ? resid : nullptr;
        unsigned short* zo = (h == 11) ? xf : nullptr;
        k_agg<<<ablocks, 256, 0, stream>>>(in, rowst, adj, sb, N_);
        k_gemm<<<gblocks, 256, 0, stream>>>(in, sb, wb + (size_t)(1 + h) * 32768,
                                            b0_h + h * 128, b1_h + h * 128, deg,
                                            outp, o32, radd, zo, N_, 1);
    }

    // last layer fused: z (in xf) -> vertices, aggregation kept in registers
    k_lastagg<<<lblocks, 256, 0, stream>>>(xf, rowst, adj, W0_l, b0_l, W1_l, b1_l,
                                           vert, N_);
}

// Round 12
// 1043.607 us; speedup vs baseline: 1.1631x; 1.0957x over previous
//
#include <hip/hip_runtime.h>
#include <hip/hip_bf16.h>

#define D 128
#define OSTR 136   // LDS row stride (shorts) for epilogue transpose
#define CHUNK 12544  // per-XCD node chunk (multiple of 64); 8*12544 >= N

typedef float f32x4  __attribute__((ext_vector_type(4)));
typedef unsigned int u32x4 __attribute__((ext_vector_type(4)));
typedef __attribute__((ext_vector_type(8))) __bf16 bh8;

union UV { uint4 u; bh8 h; };

__device__ inline float bf2f(unsigned short u) {
    union { unsigned int i; float f; } x; x.i = ((unsigned int)u) << 16; return x.f;
}
__device__ inline unsigned short f2bf(float f) {
    union { float f; unsigned int i; } x; x.f = f;
    return (unsigned short)((x.i + 0x7fffu + ((x.i >> 16) & 1u)) >> 16);
}
__device__ inline unsigned int addb2(unsigned int ua, unsigned int ub) {
    union { unsigned int i; float f; } la, ha, lb, hb;
    la.i = ua << 16; ha.i = ua & 0xffff0000u;
    lb.i = ub << 16; hb.i = ub & 0xffff0000u;
    return ((unsigned int)f2bf(ha.f + hb.f) << 16) | f2bf(la.f + lb.f);
}
__device__ inline void acc8(const uint4& u, float* aa) {
    union { unsigned int i; float f; } t;
    t.i = u.x << 16;          aa[0] += t.f;
    t.i = u.x & 0xffff0000u;  aa[1] += t.f;
    t.i = u.y << 16;          aa[2] += t.f;
    t.i = u.y & 0xffff0000u;  aa[3] += t.f;
    t.i = u.z << 16;          aa[4] += t.f;
    t.i = u.z & 0xffff0000u;  aa[5] += t.f;
    t.i = u.w << 16;          aa[6] += t.f;
    t.i = u.w & 0xffff0000u;  aa[7] += t.f;
}

// ---------------- CSR build ----------------
__global__ void k_hist(const int* __restrict__ edges, int E, int* __restrict__ deg) {
    int e = blockIdx.x * blockDim.x + threadIdx.x;
    if (e < E) {
        atomicAdd(&deg[edges[2 * e]], 1);
        atomicAdd(&deg[edges[2 * e + 1]], 1);
    }
}

__global__ void k_scan1(const int* __restrict__ deg, int n,
                        int* __restrict__ incl, int* __restrict__ bsum) {
    __shared__ int lds[1024];
    int t = threadIdx.x;
    int i = blockIdx.x * 1024 + t;
    int v = (i < n) ? deg[i] : 0;
    int cur = v;
    lds[t] = cur;
    __syncthreads();
    for (int off = 1; off < 1024; off <<= 1) {
        int add = (t >= off) ? lds[t - off] : 0;
        __syncthreads();
        cur += add;
        lds[t] = cur;
        __syncthreads();
    }
    if (i < n) incl[i] = cur;
    if (t == 1023) bsum[blockIdx.x] = cur;
}

__global__ void k_scan2(int* __restrict__ bsum, int nb) {
    __shared__ int lds[128];
    int t = threadIdx.x;
    int v = (t < nb) ? bsum[t] : 0;
    int cur = v;
    lds[t] = cur;
    __syncthreads();
    for (int off = 1; off < 128; off <<= 1) {
        int add = (t >= off) ? lds[t - off] : 0;
        __syncthreads();
        cur += add;
        lds[t] = cur;
        __syncthreads();
    }
    if (t < nb) bsum[t] = cur - v;  // exclusive
}

__global__ void k_scan3(const int* __restrict__ incl, const int* __restrict__ deg,
                        const int* __restrict__ bsum, int n, int twoE,
                        int* __restrict__ rowstart, int* __restrict__ cursor) {
    int i = blockIdx.x * blockDim.x + threadIdx.x;
    if (i < n) {
        int r = incl[i] - deg[i] + bsum[i >> 10];
        rowstart[i] = r;
        cursor[i] = r;
    }
    if (i == 0) rowstart[n] = twoE;
}

__global__ void k_fill(const int* __restrict__ edges, int E,
                       int* __restrict__ cursor, int* __restrict__ adj) {
    int e = blockIdx.x * blockDim.x + threadIdx.x;
    if (e < E) {
        int a = edges[2 * e], b = edges[2 * e + 1];
        adj[atomicAdd(&cursor[a], 1)] = b;
        adj[atomicAdd(&cursor[b], 1)] = a;
    }
}

// ---------------- weight prep: bf16, K-chunked layout ----------------
// wb[l][chunk=kk>>5][o][kk&31], kk = m*128+k (m=0: W0, m=1: W1)
__global__ void k_wprep(const float* __restrict__ W0_1, const float* __restrict__ W1_1,
                        const float* __restrict__ W0_h, const float* __restrict__ W1_h,
                        unsigned short* __restrict__ wb) {
    int idx = blockIdx.x * 256 + threadIdx.x;
    if (idx >= 13 * 2 * 128 * 128) return;
    int k = idx & 127;
    int o = (idx >> 7) & 127;
    int m = (idx >> 14) & 1;
    int l = idx >> 15;
    const float* src = (l == 0) ? (m ? W1_1 : W0_1)
                                : ((m ? W1_h : W0_h) + (size_t)(l - 1) * 16384);
    float v = src[o * 128 + k];
    int kk = m * 128 + k;
    wb[(size_t)l * 32768 + (kk >> 5) * 4096 + o * 32 + (kk & 31)] = f2bf(v);
}

// ---------------- fp32 -> bf16 convert ----------------
__global__ void k_cvt(const float* __restrict__ in, unsigned short* __restrict__ out, int n4) {
    int i = blockIdx.x * blockDim.x + threadIdx.x;
    if (i >= n4) return;
    f32x4 v = *(const f32x4*)&in[(size_t)i * 4];
    unsigned short u[4];
    #pragma unroll
    for (int j = 0; j < 4; ++j) u[j] = f2bf(v[j]);
    *(uint2*)&out[(size_t)i * 4] = *(uint2*)u;
}

// ---------------- neighbor aggregation: GROUP-PER-NODE (bf16 in/out, fp32 accum) ----------------
// 16-lane group owns one node (4 nodes/wave, 16 nodes/block). Lane c of group g
// accumulates cols 8c..8c+7 of node g in registers; one load instruction fetches
// four different 256B rows (one per group). Per node amortized: ~2 loads + 2 shfl
// + 16 adds + ~6 pack slots and ZERO cross-lane reduce (the uint4 wave-per-node
// scheme spent ~58 slots/node on reduce+pack - 3x the gather itself at deg~6).
// Groups only shfl within their own 16 active lanes (exec-mask safe).
__global__ __launch_bounds__(256) void k_agg(
    const unsigned short* __restrict__ x, const int* __restrict__ rowstart,
    const int* __restrict__ adj, unsigned short* __restrict__ s, int n) {
    int lane = threadIdx.x & 63;
    int wave = threadIdx.x >> 6;
    int g = lane >> 4;      // group 0..3 -> node
    int c = lane & 15;      // col chunk: bf16 cols 8c..8c+7
    int node = (blockIdx.x & 7) * CHUNK + (blockIdx.x >> 3) * 16 + wave * 4 + g;
    if (node >= n) return;
    int r0 = rowstart[node], r1 = rowstart[node + 1];
    float aa[8];
    #pragma unroll
    for (int k = 0; k < 8; ++k) aa[k] = 0.f;
    for (int base = r0; base < r1; base += 16) {
        int ec = base + c; if (ec > r1 - 1) ec = r1 - 1;
        int aidx = adj[ec];             // this group's next 16 edges (clamped)
        int m = r1 - base; if (m > 16) m = 16;
        uint4 u[8];
        #pragma unroll
        for (int k = 0; k < 8; ++k) {
            int j = __shfl(aidx, (g << 4) + k);
            u[k] = *(const uint4*)&x[(size_t)j * D + c * 8];
        }
        #pragma unroll
        for (int k = 0; k < 8; ++k)
            if (k < m) acc8(u[k], aa);
        if (m > 8) {
            #pragma unroll
            for (int k = 0; k < 8; ++k) {
                int j = __shfl(aidx, (g << 4) + 8 + k);
                u[k] = *(const uint4*)&x[(size_t)j * D + c * 8];
            }
            #pragma unroll
            for (int k = 0; k < 8; ++k)
                if (8 + k < m) acc8(u[k], aa);
        }
    }
    unsigned short o[8];
    #pragma unroll
    for (int k = 0; k < 8; ++k) o[k] = f2bf(aa[k]);
    *(uint4*)&s[(size_t)node * D + c * 8] = *(const uint4*)o;
}

// ---------------- MFMA GEMM: 64x128 tile, 2-stage register pipeline ----------------
// out[i][o] = act([x_i, s_i] @ [W0T;W1T] + b0 + deg*b1)
// 256 threads = 4 waves; block tile 64 nodes x 128 outs; K=256 in 8 chunks of 32.
// kc loop software-pipelined in REGISTERS: while MFMAs consume stage cs, the 6
// fragment loads of kc+1 are already in flight into stage cs^1. No LDS/barriers
// in the main loop. All stores CACHED (out is 6x-reused by next layer's gather).
__global__ __launch_bounds__(256) void k_gemm(
    const unsigned short* __restrict__ x,   // [n][128] bf16
    const unsigned short* __restrict__ s,   // [n][128] bf16
    const unsigned short* __restrict__ wb,  // layer weights, chunked [8][128][32] bf16
    const float* __restrict__ b0, const float* __restrict__ b1,
    const int* __restrict__ deg,
    unsigned short* __restrict__ out,       // [n][128] bf16
    float* __restrict__ out32,              // optional fp32 copy (aux), may be null
    const unsigned short* __restrict__ resid, // optional residual input (bf16)
    unsigned short* __restrict__ zout,      // optional: zout = out + resid
    int n, int do_relu) {
    __shared__ __align__(16) unsigned short LDS[64 * OSTR];  // 17408 B (epilogue only)
    int node0 = (blockIdx.x & 7) * CHUNK + (blockIdx.x >> 3) * 64;
    if (node0 >= n) return;
    int t = threadIdx.x;
    int lane = t & 63;
    int wave = t >> 6;
    int wm = (wave >> 1) * 32;
    int wn = (wave & 1) * 64;
    int mlane = lane & 15;
    int quad = lane >> 4;

    f32x4 acc[2][4];
    #pragma unroll
    for (int i = 0; i < 2; ++i)
        #pragma unroll
        for (int j = 0; j < 4; ++j) acc[i][j] = (f32x4){0.f, 0.f, 0.f, 0.f};

    uint4 ra[2][2];
    bh8 rb[2][4];
    auto LDK = [&](int kc, int st) {
        const unsigned short* srcA = (kc < 4) ? x : s;
        int kbase = (kc & 3) * 32;
        #pragma unroll
        for (int i = 0; i < 2; ++i) {
            int g = node0 + wm + i * 16 + mlane;
            uint4 v = {0u, 0u, 0u, 0u};
            if (g < n) v = *(const uint4*)&srcA[(size_t)g * D + kbase + quad * 8];
            ra[st][i] = v;
        }
        #pragma unroll
        for (int j = 0; j < 4; ++j)
            rb[st][j] = *(const bh8*)&wb[(size_t)kc * 4096 + (wn + j * 16 + mlane) * 32 + quad * 8];
    };

    LDK(0, 0);
    #pragma unroll
    for (int kc = 0; kc < 8; ++kc) {
        int cs = kc & 1;
        if (kc < 7) LDK(kc + 1, cs ^ 1);   // issue next-chunk loads before MFMAs
        bh8 a0, a1;
        { UV v; v.u = ra[cs][0]; a0 = v.h; }
        { UV v; v.u = ra[cs][1]; a1 = v.h; }
        #pragma unroll
        for (int j = 0; j < 4; ++j) {
            acc[0][j] = __builtin_amdgcn_mfma_f32_16x16x32_bf16(a0, rb[cs][j], acc[0][j], 0, 0, 0);
            acc[1][j] = __builtin_amdgcn_mfma_f32_16x16x32_bf16(a1, rb[cs][j], acc[1][j], 0, 0, 0);
        }
    }

    // ---- epilogue: bias + deg*b1 + relu -> LDS transpose -> coalesced stores ----
    #pragma unroll
    for (int i = 0; i < 2; ++i) {
        int mrow = wm + i * 16 + quad * 4;
        #pragma unroll
        for (int j = 0; j < 4; ++j) {
            int nn = wn + j * 16 + mlane;
            float b0v = b0[nn], b1v = b1[nn];
            #pragma unroll
            for (int r = 0; r < 4; ++r) {
                int g = node0 + mrow + r;
                float dg = (g < n) ? (float)deg[g] : 0.f;
                float val = acc[i][j][r] + b0v + dg * b1v;
                if (do_relu) val = fmaxf(val, 0.f);
                LDS[(mrow + r) * OSTR + nn] = f2bf(val);
            }
        }
    }
    __syncthreads();
    // bf16 store: 4 passes, 16 lanes x 16B = one full 256B node row per 16 threads
    #pragma unroll
    for (int pass = 0; pass < 4; ++pass) {
        int row = pass * 16 + (t >> 4);
        int seg = (t & 15) * 8;
        int g = node0 + row;
        if (g < n) {
            u32x4 v = *(const u32x4*)&LDS[row * OSTR + seg];
            *(u32x4*)&out[(size_t)g * D + seg] = v;
            if (zout) {
                u32x4 rr = *(const u32x4*)&resid[(size_t)g * D + seg];
                u32x4 zz;
                zz.x = addb2(v.x, rr.x);
                zz.y = addb2(v.y, rr.y);
                zz.z = addb2(v.z, rr.z);
                zz.w = addb2(v.w, rr.w);
                *(u32x4*)&zout[(size_t)g * D + seg] = zz;
            }
        }
    }
    if (out32) {
        #pragma unroll
        for (int pass = 0; pass < 8; ++pass) {
            int row = pass * 8 + (t >> 5);
            int seg = (t & 31) * 4;
            int g = node0 + row;
            if (g < n) {
                f32x4 v;
                #pragma unroll
                for (int j = 0; j < 4; ++j) v[j] = bf2f(LDS[row * OSTR + seg + j]);
                *(f32x4*)&out32[(size_t)g * D + seg] = v;
            }
        }
    }
}

// ---------------- fused final layer: aggregate in registers + D_out=3 dot ----------------
// wave per node, uint2 two-rows-per-load gather (round-9 proven form); lane holds
// 4 cols. 5-step half-wave shuffle reduce. Deletes the final sb round-trip.
__global__ __launch_bounds__(256) void k_lastagg(
    const unsigned short* __restrict__ z, const int* __restrict__ rowstart,
    const int* __restrict__ adj,
    const float* __restrict__ W0, const float* __restrict__ b0,
    const float* __restrict__ W1, const float* __restrict__ b1,
    float* __restrict__ vert, int n) {
    int node = blockIdx.x * 4 + (threadIdx.x >> 6);
    int lane = threadIdx.x & 63;
    if (node >= n) return;
    int r0 = rowstart[node], r1 = rowstart[node + 1];
    int c  = lane & 31;
    int hi = lane >> 5;
    float aa0 = 0.f, aa1 = 0.f, aa2 = 0.f, aa3 = 0.f;
    for (int p = r0; p < r1; p += 8) {
        int q = p + (lane & 7);
        int idx = (q < r1) ? adj[q] : adj[r0];
        uint2 u[4];
        #pragma unroll
        for (int k = 0; k < 4; ++k) {
            int j = __shfl(idx, 2 * k + hi);
            u[k] = *(const uint2*)&z[(size_t)j * D + c * 4];
        }
        #pragma unroll
        for (int k = 0; k < 4; ++k) {
            if (p + 2 * k + hi < r1) {
                union { unsigned int i; float f; } t;
                t.i = u[k].x << 16;          aa0 += t.f;
                t.i = u[k].x & 0xffff0000u;  aa1 += t.f;
                t.i = u[k].y << 16;          aa2 += t.f;
                t.i = u[k].y & 0xffff0000u;  aa3 += t.f;
            }
        }
    }
    aa0 += __shfl_xor(aa0, 32);
    aa1 += __shfl_xor(aa1, 32);
    aa2 += __shfl_xor(aa2, 32);
    aa3 += __shfl_xor(aa3, 32);
    // own row z[node], cols 4c..4c+3 (both halves load identical values)
    uint2 zz = *(const uint2*)&z[(size_t)node * D + c * 4];
    float z0, z1, z2, z3;
    { union { unsigned int i; float f; } t;
      t.i = zz.x << 16;         z0 = t.f;
      t.i = zz.x & 0xffff0000u; z1 = t.f;
      t.i = zz.y << 16;         z2 = t.f;
      t.i = zz.y & 0xffff0000u; z3 = t.f; }
    float dg = (float)(r1 - r0);
    #pragma unroll
    for (int o = 0; o < 3; ++o) {
        f32x4 w0 = *(const f32x4*)&W0[o * D + 4 * c];
        f32x4 w1 = *(const f32x4*)&W1[o * D + 4 * c];
        float p = z0 * w0[0] + z1 * w0[1] + z2 * w0[2] + z3 * w0[3]
                + aa0 * w1[0] + aa1 * w1[1] + aa2 * w1[2] + aa3 * w1[3];
        p += __shfl_xor(p, 16);
        p += __shfl_xor(p, 8);
        p += __shfl_xor(p, 4);
        p += __shfl_xor(p, 2);
        p += __shfl_xor(p, 1);
        if (lane == 0) vert[(size_t)node * 3 + o] = p + b0[o] + dg * b1[o];
    }
}

extern "C" void kernel_launch(void* const* d_in, const int* in_sizes, int n_in,
                              void* d_out, int out_size, void* d_ws, size_t ws_size,
                              hipStream_t stream) {
    const float* features = (const float*)d_in[0];
    const int*   edges    = (const int*)d_in[1];
    const float* W0_1 = (const float*)d_in[2];
    const float* b0_1 = (const float*)d_in[3];
    const float* W1_1 = (const float*)d_in[4];
    const float* b1_1 = (const float*)d_in[5];
    const float* W0_h = (const float*)d_in[6];
    const float* b0_h = (const float*)d_in[7];
    const float* W1_h = (const float*)d_in[8];
    const float* b1_h = (const float*)d_in[9];
    const float* W0_l = (const float*)d_in[10];
    const float* b0_l = (const float*)d_in[11];
    const float* W1_l = (const float*)d_in[12];
    const float* b1_l = (const float*)d_in[13];

    const int N_ = 100000, E_ = 300000;
    float* vert = (float*)d_out;                    // N*3
    float* aux  = (float*)d_out + (size_t)N_ * 3;   // N*128 fp32

    char* w = (char*)d_ws;
    auto alloc = [&](size_t bytes) {
        char* p = w;
        w += (bytes + 255) & ~(size_t)255;
        return p;
    };
    unsigned short* wb    = (unsigned short*)alloc((size_t)13 * 32768 * 2);
    unsigned short* xf    = (unsigned short*)alloc((size_t)N_ * D * 2);
    unsigned short* resid = (unsigned short*)alloc((size_t)N_ * D * 2);
    unsigned short* xa    = (unsigned short*)alloc((size_t)N_ * D * 2);
    unsigned short* xb    = (unsigned short*)alloc((size_t)N_ * D * 2);
    unsigned short* sb    = (unsigned short*)alloc((size_t)N_ * D * 2);
    int* deg    = (int*)alloc((size_t)N_ * 4);
    int* incl   = (int*)alloc((size_t)N_ * 4);
    int* rowst  = (int*)alloc((size_t)(N_ + 1) * 4);
    int* cursor = (int*)alloc((size_t)N_ * 4);
    int* bsum   = (int*)alloc(128 * 4);
    int* adj    = (int*)alloc((size_t)2 * E_ * 4);

    // CSR build
    hipMemsetAsync(deg, 0, (size_t)N_ * 4, stream);
    k_hist<<<(E_ + 255) / 256, 256, 0, stream>>>(edges, E_, deg);
    int nb = (N_ + 1023) / 1024;   // 98
    k_scan1<<<nb, 1024, 0, stream>>>(deg, N_, incl, bsum);
    k_scan2<<<1, 128, 0, stream>>>(bsum, nb);
    k_scan3<<<(N_ + 255) / 256, 256, 0, stream>>>(incl, deg, bsum, N_, 2 * E_, rowst, cursor);
    k_fill<<<(E_ + 255) / 256, 256, 0, stream>>>(edges, E_, cursor, adj);

    // weight + feature conversion
    k_wprep<<<(13 * 2 * 16384 + 255) / 256, 256, 0, stream>>>(W0_1, W1_1, W0_h, W1_h, wb);
    k_cvt<<<(N_ * D / 4 + 255) / 256, 256, 0, stream>>>(features, xf, N_ * D / 4);

    // XCD-chunked grids: xcd = blockIdx%8, chunk = CHUNK nodes
    int gblocks = 8 * ((CHUNK) / 64);    // 8 * 196 = 1568
    int ablocks = 8 * ((CHUNK) / 16);    // 8 * 784 = 6272 (16 nodes/block)
    int lblocks = (N_ + 3) / 4;          // k_lastagg

    // layer 1: xf -> resid
    k_agg<<<ablocks, 256, 0, stream>>>(xf, rowst, adj, sb, N_);
    k_gemm<<<gblocks, 256, 0, stream>>>(xf, sb, wb, b0_1, b1_1, deg, resid,
                                        nullptr, nullptr, nullptr, N_, 1);

    // 12 hidden layers; layer 12 also writes aux (fp32) and z = resid + x12 -> xf
    for (int h = 0; h < 12; ++h) {
        const unsigned short* in = (h == 0) ? resid : ((h & 1) ? xa : xb);
        unsigned short* outp = (h & 1) ? xb : xa;
        float* o32 = (h == 11) ? aux : nullptr;
        const unsigned short* radd = (h == 11) ? resid : nullptr;
        unsigned short* zo = (h == 11) ? xf : nullptr;
        k_agg<<<ablocks, 256, 0, stream>>>(in, rowst, adj, sb, N_);
        k_gemm<<<gblocks, 256, 0, stream>>>(in, sb, wb + (size_t)(1 + h) * 32768,
                                            b0_h + h * 128, b1_h + h * 128, deg,
                                            outp, o32, radd, zo, N_, 1);
    }

    // last layer fused: z (in xf) -> vertices, aggregation kept in registers
    k_lastagg<<<lblocks, 256, 0, stream>>>(xf, rowst, adj, W0_l, b0_l, W1_l, b1_l,
                                           vert, N_);
}

// Round 13
// 1016.727 us; speedup vs baseline: 1.1939x; 1.0264x over previous
//
#include <hip/hip_runtime.h>
#include <hip/hip_bf16.h>

#define D 128
#define OSTR 136   // LDS row stride (shorts) for epilogue transpose
#define CHUNK 12544  // per-XCD node chunk (multiple of 64); 8*12544 >= N

typedef float f32x4  __attribute__((ext_vector_type(4)));
typedef unsigned int u32x4 __attribute__((ext_vector_type(4)));
typedef __attribute__((ext_vector_type(8))) __bf16 bh8;

union UV { uint4 u; bh8 h; };

__device__ inline float bf2f(unsigned short u) {
    union { unsigned int i; float f; } x; x.i = ((unsigned int)u) << 16; return x.f;
}
__device__ inline unsigned short f2bf(float f) {
    union { float f; unsigned int i; } x; x.f = f;
    return (unsigned short)((x.i + 0x7fffu + ((x.i >> 16) & 1u)) >> 16);
}
__device__ inline unsigned int addb2(unsigned int ua, unsigned int ub) {
    union { unsigned int i; float f; } la, ha, lb, hb;
    la.i = ua << 16; ha.i = ua & 0xffff0000u;
    lb.i = ub << 16; hb.i = ub & 0xffff0000u;
    return ((unsigned int)f2bf(ha.f + hb.f) << 16) | f2bf(la.f + lb.f);
}
__device__ inline void acc8(const uint4& u, float* aa) {
    union { unsigned int i; float f; } t;
    t.i = u.x << 16;          aa[0] += t.f;
    t.i = u.x & 0xffff0000u;  aa[1] += t.f;
    t.i = u.y << 16;          aa[2] += t.f;
    t.i = u.y & 0xffff0000u;  aa[3] += t.f;
    t.i = u.z << 16;          aa[4] += t.f;
    t.i = u.z & 0xffff0000u;  aa[5] += t.f;
    t.i = u.w << 16;          aa[6] += t.f;
    t.i = u.w & 0xffff0000u;  aa[7] += t.f;
}

// ---------------- CSR build ----------------
__global__ void k_hist(const int* __restrict__ edges, int E, int* __restrict__ deg) {
    int e = blockIdx.x * blockDim.x + threadIdx.x;
    if (e < E) {
        atomicAdd(&deg[edges[2 * e]], 1);
        atomicAdd(&deg[edges[2 * e + 1]], 1);
    }
}

__global__ void k_scan1(const int* __restrict__ deg, int n,
                        int* __restrict__ incl, int* __restrict__ bsum) {
    __shared__ int lds[1024];
    int t = threadIdx.x;
    int i = blockIdx.x * 1024 + t;
    int v = (i < n) ? deg[i] : 0;
    int cur = v;
    lds[t] = cur;
    __syncthreads();
    for (int off = 1; off < 1024; off <<= 1) {
        int add = (t >= off) ? lds[t - off] : 0;
        __syncthreads();
        cur += add;
        lds[t] = cur;
        __syncthreads();
    }
    if (i < n) incl[i] = cur;
    if (t == 1023) bsum[blockIdx.x] = cur;
}

__global__ void k_scan2(int* __restrict__ bsum, int nb) {
    __shared__ int lds[128];
    int t = threadIdx.x;
    int v = (t < nb) ? bsum[t] : 0;
    int cur = v;
    lds[t] = cur;
    __syncthreads();
    for (int off = 1; off < 128; off <<= 1) {
        int add = (t >= off) ? lds[t - off] : 0;
        __syncthreads();
        cur += add;
        lds[t] = cur;
        __syncthreads();
    }
    if (t < nb) bsum[t] = cur - v;  // exclusive
}

__global__ void k_scan3(const int* __restrict__ incl, const int* __restrict__ deg,
                        const int* __restrict__ bsum, int n, int twoE,
                        int* __restrict__ rowstart, int* __restrict__ cursor) {
    int i = blockIdx.x * blockDim.x + threadIdx.x;
    if (i < n) {
        int r = incl[i] - deg[i] + bsum[i >> 10];
        rowstart[i] = r;
        cursor[i] = r;
    }
    if (i == 0) rowstart[n] = twoE;
}

__global__ void k_fill(const int* __restrict__ edges, int E,
                       int* __restrict__ cursor, int* __restrict__ adj) {
    int e = blockIdx.x * blockDim.x + threadIdx.x;
    if (e < E) {
        int a = edges[2 * e], b = edges[2 * e + 1];
        adj[atomicAdd(&cursor[a], 1)] = b;
        adj[atomicAdd(&cursor[b], 1)] = a;
    }
}

// ---------------- weight prep: bf16, K-chunked layout ----------------
// wb[l][chunk=kk>>5][o][kk&31], kk = m*128+k (m=0: W0, m=1: W1)
__global__ void k_wprep(const float* __restrict__ W0_1, const float* __restrict__ W1_1,
                        const float* __restrict__ W0_h, const float* __restrict__ W1_h,
                        unsigned short* __restrict__ wb) {
    int idx = blockIdx.x * 256 + threadIdx.x;
    if (idx >= 13 * 2 * 128 * 128) return;
    int k = idx & 127;
    int o = (idx >> 7) & 127;
    int m = (idx >> 14) & 1;
    int l = idx >> 15;
    const float* src = (l == 0) ? (m ? W1_1 : W0_1)
                                : ((m ? W1_h : W0_h) + (size_t)(l - 1) * 16384);
    float v = src[o * 128 + k];
    int kk = m * 128 + k;
    wb[(size_t)l * 32768 + (kk >> 5) * 4096 + o * 32 + (kk & 31)] = f2bf(v);
}

// ---------------- fp32 -> bf16 convert ----------------
__global__ void k_cvt(const float* __restrict__ in, unsigned short* __restrict__ out, int n4) {
    int i = blockIdx.x * blockDim.x + threadIdx.x;
    if (i >= n4) return;
    f32x4 v = *(const f32x4*)&in[(size_t)i * 4];
    unsigned short u[4];
    #pragma unroll
    for (int j = 0; j < 4; ++j) u[j] = f2bf(v[j]);
    *(uint2*)&out[(size_t)i * 4] = *(uint2*)u;
}

// ---------------- neighbor aggregation: GROUP-PER-NODE (bf16 in/out, fp32 accum) ----------------
// 16-lane group owns one node (4 nodes/wave, 16 nodes/block). Lane c of group g
// accumulates cols 8c..8c+7 of node g in registers; one load instruction fetches
// four different 256B rows (one per group). Zero cross-lane reduce.
__global__ __launch_bounds__(256) void k_agg(
    const unsigned short* __restrict__ x, const int* __restrict__ rowstart,
    const int* __restrict__ adj, unsigned short* __restrict__ s, int n) {
    int lane = threadIdx.x & 63;
    int wave = threadIdx.x >> 6;
    int g = lane >> 4;      // group 0..3 -> node
    int c = lane & 15;      // col chunk: bf16 cols 8c..8c+7
    int node = (blockIdx.x & 7) * CHUNK + (blockIdx.x >> 3) * 16 + wave * 4 + g;
    if (node >= n) return;
    int r0 = rowstart[node], r1 = rowstart[node + 1];
    float aa[8];
    #pragma unroll
    for (int k = 0; k < 8; ++k) aa[k] = 0.f;
    for (int base = r0; base < r1; base += 16) {
        int ec = base + c; if (ec > r1 - 1) ec = r1 - 1;
        int aidx = adj[ec];             // this group's next 16 edges (clamped)
        int m = r1 - base; if (m > 16) m = 16;
        uint4 u[8];
        #pragma unroll
        for (int k = 0; k < 8; ++k) {
            int j = __shfl(aidx, (g << 4) + k);
            u[k] = *(const uint4*)&x[(size_t)j * D + c * 8];
        }
        #pragma unroll
        for (int k = 0; k < 8; ++k)
            if (k < m) acc8(u[k], aa);
        if (m > 8) {
            #pragma unroll
            for (int k = 0; k < 8; ++k) {
                int j = __shfl(aidx, (g << 4) + 8 + k);
                u[k] = *(const uint4*)&x[(size_t)j * D + c * 8];
            }
            #pragma unroll
            for (int k = 0; k < 8; ++k)
                if (8 + k < m) acc8(u[k], aa);
        }
    }
    unsigned short o[8];
    #pragma unroll
    for (int k = 0; k < 8; ++k) o[k] = f2bf(aa[k]);
    *(uint4*)&s[(size_t)node * D + c * 8] = *(const uint4*)o;
}

// ---------------- MFMA GEMM: 64x128 tile, 2-stage register pipeline ----------------
// out[i][o] = act([x_i, s_i] @ [W0T;W1T] + b0 + deg*b1)
// 256 threads = 4 waves; block tile 64 nodes x 128 outs; K=256 in 8 chunks of 32.
// kc loop software-pipelined in REGISTERS. No LDS/barriers in the main loop.
__global__ __launch_bounds__(256) void k_gemm(
    const unsigned short* __restrict__ x,   // [n][128] bf16
    const unsigned short* __restrict__ s,   // [n][128] bf16
    const unsigned short* __restrict__ wb,  // layer weights, chunked [8][128][32] bf16
    const float* __restrict__ b0, const float* __restrict__ b1,
    const int* __restrict__ deg,
    unsigned short* __restrict__ out,       // [n][128] bf16
    float* __restrict__ out32,              // optional fp32 copy (aux), may be null
    const unsigned short* __restrict__ resid, // optional residual input (bf16)
    unsigned short* __restrict__ zout,      // optional: zout = out + resid
    int n, int do_relu) {
    __shared__ __align__(16) unsigned short LDS[64 * OSTR];  // 17408 B (epilogue only)
    int node0 = (blockIdx.x & 7) * CHUNK + (blockIdx.x >> 3) * 64;
    if (node0 >= n) return;
    int t = threadIdx.x;
    int lane = t & 63;
    int wave = t >> 6;
    int wm = (wave >> 1) * 32;
    int wn = (wave & 1) * 64;
    int mlane = lane & 15;
    int quad = lane >> 4;

    f32x4 acc[2][4];
    #pragma unroll
    for (int i = 0; i < 2; ++i)
        #pragma unroll
        for (int j = 0; j < 4; ++j) acc[i][j] = (f32x4){0.f, 0.f, 0.f, 0.f};

    uint4 ra[2][2];
    bh8 rb[2][4];
    auto LDK = [&](int kc, int st) {
        const unsigned short* srcA = (kc < 4) ? x : s;
        int kbase = (kc & 3) * 32;
        #pragma unroll
        for (int i = 0; i < 2; ++i) {
            int g = node0 + wm + i * 16 + mlane;
            uint4 v = {0u, 0u, 0u, 0u};
            if (g < n) v = *(const uint4*)&srcA[(size_t)g * D + kbase + quad * 8];
            ra[st][i] = v;
        }
        #pragma unroll
        for (int j = 0; j < 4; ++j)
            rb[st][j] = *(const bh8*)&wb[(size_t)kc * 4096 + (wn + j * 16 + mlane) * 32 + quad * 8];
    };

    LDK(0, 0);
    #pragma unroll
    for (int kc = 0; kc < 8; ++kc) {
        int cs = kc & 1;
        if (kc < 7) LDK(kc + 1, cs ^ 1);   // issue next-chunk loads before MFMAs
        bh8 a0, a1;
        { UV v; v.u = ra[cs][0]; a0 = v.h; }
        { UV v; v.u = ra[cs][1]; a1 = v.h; }
        #pragma unroll
        for (int j = 0; j < 4; ++j) {
            acc[0][j] = __builtin_amdgcn_mfma_f32_16x16x32_bf16(a0, rb[cs][j], acc[0][j], 0, 0, 0);
            acc[1][j] = __builtin_amdgcn_mfma_f32_16x16x32_bf16(a1, rb[cs][j], acc[1][j], 0, 0, 0);
        }
    }

    // ---- epilogue: bias + deg*b1 + relu -> LDS transpose -> coalesced stores ----
    #pragma unroll
    for (int i = 0; i < 2; ++i) {
        int mrow = wm + i * 16 + quad * 4;
        #pragma unroll
        for (int j = 0; j < 4; ++j) {
            int nn = wn + j * 16 + mlane;
            float b0v = b0[nn], b1v = b1[nn];
            #pragma unroll
            for (int r = 0; r < 4; ++r) {
                int g = node0 + mrow + r;
                float dg = (g < n) ? (float)deg[g] : 0.f;
                float val = acc[i][j][r] + b0v + dg * b1v;
                if (do_relu) val = fmaxf(val, 0.f);
                LDS[(mrow + r) * OSTR + nn] = f2bf(val);
            }
        }
    }
    __syncthreads();
    // bf16 store: 4 passes, 16 lanes x 16B = one full 256B node row per 16 threads
    #pragma unroll
    for (int pass = 0; pass < 4; ++pass) {
        int row = pass * 16 + (t >> 4);
        int seg = (t & 15) * 8;
        int g = node0 + row;
        if (g < n) {
            u32x4 v = *(const u32x4*)&LDS[row * OSTR + seg];
            *(u32x4*)&out[(size_t)g * D + seg] = v;
            if (zout) {
                u32x4 rr = *(const u32x4*)&resid[(size_t)g * D + seg];
                u32x4 zz;
                zz.x = addb2(v.x, rr.x);
                zz.y = addb2(v.y, rr.y);
                zz.z = addb2(v.z, rr.z);
                zz.w = addb2(v.w, rr.w);
                *(u32x4*)&zout[(size_t)g * D + seg] = zz;
            }
        }
    }
    if (out32) {
        #pragma unroll
        for (int pass = 0; pass < 8; ++pass) {
            int row = pass * 8 + (t >> 5);
            int seg = (t & 31) * 4;
            int g = node0 + row;
            if (g < n) {
                f32x4 v;
                #pragma unroll
                for (int j = 0; j < 4; ++j) v[j] = bf2f(LDS[row * OSTR + seg + j]);
                *(f32x4*)&out32[(size_t)g * D + seg] = v;
            }
        }
    }
}

// ---------------- fused final layer: GROUP-PER-NODE gather + D_out=3 dot ----------------
// 16-lane group owns one node (4 nodes/wave, 16/block). Gather identical to
// k_agg (zero cross-lane combine; lane c holds col-sums 8c..8c+7 in registers).
// Own row = one uint4/lane. Dots: 16 FMA/lane per output + 4-step in-group
// shfl_xor reduce. Per-node issue cost ~40 slots vs ~100 for wave-per-node.
__global__ __launch_bounds__(256) void k_lastagg(
    const unsigned short* __restrict__ z, const int* __restrict__ rowstart,
    const int* __restrict__ adj,
    const float* __restrict__ W0, const float* __restrict__ b0,
    const float* __restrict__ W1, const float* __restrict__ b1,
    float* __restrict__ vert, int n) {
    int lane = threadIdx.x & 63;
    int wave = threadIdx.x >> 6;
    int g = lane >> 4;      // group 0..3 -> node
    int c = lane & 15;      // col chunk: bf16 cols 8c..8c+7
    int node = blockIdx.x * 16 + wave * 4 + g;
    if (node >= n) return;
    int r0 = rowstart[node], r1 = rowstart[node + 1];
    float aa[8];
    #pragma unroll
    for (int k = 0; k < 8; ++k) aa[k] = 0.f;
    for (int base = r0; base < r1; base += 16) {
        int ec = base + c; if (ec > r1 - 1) ec = r1 - 1;
        int aidx = adj[ec];
        int m = r1 - base; if (m > 16) m = 16;
        uint4 u[8];
        #pragma unroll
        for (int k = 0; k < 8; ++k) {
            int j = __shfl(aidx, (g << 4) + k);
            u[k] = *(const uint4*)&z[(size_t)j * D + c * 8];
        }
        #pragma unroll
        for (int k = 0; k < 8; ++k)
            if (k < m) acc8(u[k], aa);
        if (m > 8) {
            #pragma unroll
            for (int k = 0; k < 8; ++k) {
                int j = __shfl(aidx, (g << 4) + 8 + k);
                u[k] = *(const uint4*)&z[(size_t)j * D + c * 8];
            }
            #pragma unroll
            for (int k = 0; k < 8; ++k)
                if (8 + k < m) acc8(u[k], aa);
        }
    }
    // own row z[node], cols 8c..8c+7
    float zf[8];
    {
        uint4 zz = *(const uint4*)&z[(size_t)node * D + c * 8];
        union { unsigned int i; float f; } t;
        t.i = zz.x << 16;          zf[0] = t.f;
        t.i = zz.x & 0xffff0000u;  zf[1] = t.f;
        t.i = zz.y << 16;          zf[2] = t.f;
        t.i = zz.y & 0xffff0000u;  zf[3] = t.f;
        t.i = zz.z << 16;          zf[4] = t.f;
        t.i = zz.z & 0xffff0000u;  zf[5] = t.f;
        t.i = zz.w << 16;          zf[6] = t.f;
        t.i = zz.w & 0xffff0000u;  zf[7] = t.f;
    }
    float dg = (float)(r1 - r0);
    #pragma unroll
    for (int o = 0; o < 3; ++o) {
        f32x4 w0a = *(const f32x4*)&W0[o * D + 8 * c];
        f32x4 w0b = *(const f32x4*)&W0[o * D + 8 * c + 4];
        f32x4 w1a = *(const f32x4*)&W1[o * D + 8 * c];
        f32x4 w1b = *(const f32x4*)&W1[o * D + 8 * c + 4];
        float p = zf[0] * w0a[0] + zf[1] * w0a[1] + zf[2] * w0a[2] + zf[3] * w0a[3]
                + zf[4] * w0b[0] + zf[5] * w0b[1] + zf[6] * w0b[2] + zf[7] * w0b[3]
                + aa[0] * w1a[0] + aa[1] * w1a[1] + aa[2] * w1a[2] + aa[3] * w1a[3]
                + aa[4] * w1b[0] + aa[5] * w1b[1] + aa[6] * w1b[2] + aa[7] * w1b[3];
        p += __shfl_xor(p, 8);
        p += __shfl_xor(p, 4);
        p += __shfl_xor(p, 2);
        p += __shfl_xor(p, 1);
        if (c == 0) vert[(size_t)node * 3 + o] = p + b0[o] + dg * b1[o];
    }
}

extern "C" void kernel_launch(void* const* d_in, const int* in_sizes, int n_in,
                              void* d_out, int out_size, void* d_ws, size_t ws_size,
                              hipStream_t stream) {
    const float* features = (const float*)d_in[0];
    const int*   edges    = (const int*)d_in[1];
    const float* W0_1 = (const float*)d_in[2];
    const float* b0_1 = (const float*)d_in[3];
    const float* W1_1 = (const float*)d_in[4];
    const float* b1_1 = (const float*)d_in[5];
    const float* W0_h = (const float*)d_in[6];
    const float* b0_h = (const float*)d_in[7];
    const float* W1_h = (const float*)d_in[8];
    const float* b1_h = (const float*)d_in[9];
    const float* W0_l = (const float*)d_in[10];
    const float* b0_l = (const float*)d_in[11];
    const float* W1_l = (const float*)d_in[12];
    const float* b1_l = (const float*)d_in[13];

    const int N_ = 100000, E_ = 300000;
    float* vert = (float*)d_out;                    // N*3
    float* aux  = (float*)d_out + (size_t)N_ * 3;   // N*128 fp32

    char* w = (char*)d_ws;
    auto alloc = [&](size_t bytes) {
        char* p = w;
        w += (bytes + 255) & ~(size_t)255;
        return p;
    };
    unsigned short* wb    = (unsigned short*)alloc((size_t)13 * 32768 * 2);
    unsigned short* xf    = (unsigned short*)alloc((size_t)N_ * D * 2);
    unsigned short* resid = (unsigned short*)alloc((size_t)N_ * D * 2);
    unsigned short* xa    = (unsigned short*)alloc((size_t)N_ * D * 2);
    unsigned short* xb    = (unsigned short*)alloc((size_t)N_ * D * 2);
    unsigned short* sb    = (unsigned short*)alloc((size_t)N_ * D * 2);
    int* deg    = (int*)alloc((size_t)N_ * 4);
    int* incl   = (int*)alloc((size_t)N_ * 4);
    int* rowst  = (int*)alloc((size_t)(N_ + 1) * 4);
    int* cursor = (int*)alloc((size_t)N_ * 4);
    int* bsum   = (int*)alloc(128 * 4);
    int* adj    = (int*)alloc((size_t)2 * E_ * 4);

    // CSR build
    hipMemsetAsync(deg, 0, (size_t)N_ * 4, stream);
    k_hist<<<(E_ + 255) / 256, 256, 0, stream>>>(edges, E_, deg);
    int nb = (N_ + 1023) / 1024;   // 98
    k_scan1<<<nb, 1024, 0, stream>>>(deg, N_, incl, bsum);
    k_scan2<<<1, 128, 0, stream>>>(bsum, nb);
    k_scan3<<<(N_ + 255) / 256, 256, 0, stream>>>(incl, deg, bsum, N_, 2 * E_, rowst, cursor);
    k_fill<<<(E_ + 255) / 256, 256, 0, stream>>>(edges, E_, cursor, adj);

    // weight + feature conversion
    k_wprep<<<(13 * 2 * 16384 + 255) / 256, 256, 0, stream>>>(W0_1, W1_1, W0_h, W1_h, wb);
    k_cvt<<<(N_ * D / 4 + 255) / 256, 256, 0, stream>>>(features, xf, N_ * D / 4);

    // XCD-chunked grids: xcd = blockIdx%8, chunk = CHUNK nodes
    int gblocks = 8 * ((CHUNK) / 64);    // 8 * 196 = 1568
    int ablocks = 8 * ((CHUNK) / 16);    // 8 * 784 = 6272 (16 nodes/block)
    int lblocks = (N_ + 15) / 16;        // k_lastagg (16 nodes/block)

    // layer 1: xf -> resid
    k_agg<<<ablocks, 256, 0, stream>>>(xf, rowst, adj, sb, N_);
    k_gemm<<<gblocks, 256, 0, stream>>>(xf, sb, wb, b0_1, b1_1, deg, resid,
                                        nullptr, nullptr, nullptr, N_, 1);

    // 12 hidden layers; layer 12 also writes aux (fp32) and z = resid + x12 -> xf
    for (int h = 0; h < 12; ++h) {
        const unsigned short* in = (h == 0) ? resid : ((h & 1) ? xa : xb);
        unsigned short* outp = (h & 1) ? xb : xa;
        float* o32 = (h == 11) ? aux : nullptr;
        const unsigned short* radd = (h == 11) ? resid : nullptr;
        unsigned short* zo = (h == 11) ? xf : nullptr;
        k_agg<<<ablocks, 256, 0, stream>>>(in, rowst, adj, sb, N_);
        k_gemm<<<gblocks, 256, 0, stream>>>(in, sb, wb + (size_t)(1 + h) * 32768,
                                            b0_h + h * 128, b1_h + h * 128, deg,
                                            outp, o32, radd, zo, N_, 1);
    }

    // last layer fused: z (in xf) -> vertices, aggregation kept in registers
    k_lastagg<<<lblocks, 256, 0, stream>>>(xf, rowst, adj, W0_l, b0_l, W1_l, b1_l,
                                           vert, N_);
}